// Round 5
// baseline (1892.412 us; speedup 1.0000x reference)
//
#include <hip/hip_runtime.h>
#include <hip/hip_bf16.h>

// ZINC GINE inner, round 5: CSR + chunked emsg, all-bf16 activations, <=190MB ws.
// h bf16 [N,128]; a0 bf16 [N,128] (u/t/z in-place); emsg chunk bf16 (E/2)x128.
// Gather: zero atomics (dst-sorted edges, per-chunk RMW). BN stats f32-exact.

#define BNEPS 1e-5f
#define LDA 136   // 128 + 8 shorts pad

typedef __attribute__((ext_vector_type(8))) short bf16x8;
typedef __attribute__((ext_vector_type(4))) float f32x4;

__device__ inline short f2bf(float f) {
    __hip_bfloat16 h = __float2bfloat16(f);
    return *reinterpret_cast<short*>(&h);
}
__device__ inline unsigned short f2bfu(float f) {
    __hip_bfloat16 h = __float2bfloat16(f);
    return *reinterpret_cast<unsigned short*>(&h);
}
__device__ inline float bf2f(unsigned short u) {
    union { unsigned int i; float f; } v; v.i = ((unsigned int)u) << 16; return v.f;
}

// ---------------- prep: transpose 10 f32 [128,128] weights -> bf16 W^T ----------------
__global__ __launch_bounds__(256) void k_prep(
    const float* __restrict__ m1W2, const float* __restrict__ beW2,
    const float* __restrict__ mW1, const float* __restrict__ mW2,
    short* __restrict__ out)
{
    __shared__ float tileS[64][65];
    int b = blockIdx.x, mat = b >> 2, t = b & 3;
    const float* Wsrc;
    if (mat == 0) Wsrc = m1W2;
    else {
        int l = (mat - 1) / 3, which = (mat - 1) % 3;
        Wsrc = (which == 0) ? beW2 + (size_t)l * 16384
             : (which == 1) ? mW1 + (size_t)l * 16384
             :                mW2 + (size_t)l * 16384;
    }
    short* dst = out + (size_t)mat * 16384;
    int tr = (t >> 1) * 64, tc = (t & 1) * 64;
    for (int i = threadIdx.x; i < 4096; i += 256) {
        int r = i >> 6, c = i & 63;
        tileS[r][c] = Wsrc[(size_t)(tr + r) * 128 + (tc + c)];
    }
    __syncthreads();
    for (int i = threadIdx.x; i < 4096; i += 256) {
        int n = i >> 6, k = i & 63;
        dst[(size_t)(tc + n) * 128 + (tr + k)] = f2bf(tileS[k][n]);
    }
}

// ---------------- CSR build ----------------
__global__ __launch_bounds__(256) void k_count(
    const int* __restrict__ ei, int* __restrict__ counts, int E)
{
    for (int e = blockIdx.x * 256 + threadIdx.x; e < E; e += gridDim.x * 256)
        atomicAdd(&counts[ei[E + e]], 1);
}

__global__ __launch_bounds__(1024) void k_scan(
    const int* __restrict__ counts, int* __restrict__ offsets,
    int* __restrict__ cursor, int N)
{
    __shared__ int part[1024];
    int tid = threadIdx.x;
    int chunk = (N + 1023) >> 10;
    int lo = tid * chunk, hi = min(lo + chunk, N);
    int s = 0;
    for (int i = lo; i < hi; ++i) s += counts[i];
    part[tid] = s;
    __syncthreads();
    for (int d = 1; d < 1024; d <<= 1) {
        int v = (tid >= d) ? part[tid - d] : 0;
        __syncthreads();
        part[tid] += v;
        __syncthreads();
    }
    int base = (tid == 0) ? 0 : part[tid - 1];
    for (int i = lo; i < hi; ++i) {
        int c = counts[i];
        offsets[i] = base; cursor[i] = base;
        base += c;
    }
    if (tid == 1023) offsets[N] = part[1023];
}

__global__ __launch_bounds__(256) void k_scatter(
    const int* __restrict__ ei, const float* __restrict__ ew,
    int* __restrict__ cursor, int* __restrict__ perm, int2* __restrict__ pmeta, int E)
{
    for (int e = blockIdx.x * 256 + threadIdx.x; e < E; e += gridDim.x * 256) {
        int d = ei[E + e];
        int pos = atomicAdd(&cursor[d], 1);
        perm[pos] = e;
        pmeta[pos] = make_int2(ei[e], __float_as_int(ew[e]));
    }
}

// ---------------- hidden edge GEMM over sorted chunk [e0,e1): emsg = MLP(ea[perm[k]]) ----------------
__global__ __launch_bounds__(256) void k_emsg(
    const int* __restrict__ perm, const float4* __restrict__ ea4,
    const float* __restrict__ W1, const float* __restrict__ b1,
    const short* __restrict__ W2t, const float* __restrict__ b2,
    unsigned short* __restrict__ emsg, int e0, int e1)
{
    __shared__ short Bs[128 * LDA];
    __shared__ short As[64 * LDA];
    __shared__ float eas[64][4];
    int tid = threadIdx.x;
    for (int i = tid; i < 2048; i += 256) {
        int n = (i * 8) >> 7, k = (i * 8) & 127;
        *(bf16x8*)&Bs[n * LDA + k] = *(const bf16x8*)&W2t[i * 8];
    }
    int j = tid & 127, half = tid >> 7;
    float w10 = W1[j], w11 = W1[128 + j], w12 = W1[256 + j], w13 = W1[384 + j];
    float b1j = b1[j];
    int w = tid >> 6, lane = tid & 63;
    int l15 = lane & 15, quad = lane >> 4;
    __syncthreads();

    int numTiles = (e1 - e0 + 63) >> 6;
    for (int tile = blockIdx.x; tile < numTiles; tile += gridDim.x) {
        int base = e0 + tile * 64;
        __syncthreads();   // protect eas/As from previous iteration readers
        if (tid < 64) {
            int k = base + tid;
            float4 a = make_float4(0.f, 0.f, 0.f, 0.f);
            if (k < e1) a = ea4[perm[k]];
            eas[tid][0] = a.x; eas[tid][1] = a.y; eas[tid][2] = a.z; eas[tid][3] = a.w;
        }
        __syncthreads();
        #pragma unroll
        for (int q = 0; q < 32; ++q) {
            int e = half * 32 + q;
            float t = fmaf(eas[e][0], w10, fmaf(eas[e][1], w11,
                      fmaf(eas[e][2], w12, fmaf(eas[e][3], w13, b1j))));
            As[e * LDA + j] = f2bf(fmaxf(t, 0.f));
        }
        __syncthreads();
        f32x4 acc[8];
        #pragma unroll
        for (int nt = 0; nt < 8; ++nt) acc[nt] = (f32x4){0.f, 0.f, 0.f, 0.f};
        #pragma unroll
        for (int kt = 0; kt < 4; ++kt) {
            bf16x8 af = *(bf16x8*)&As[(w * 16 + l15) * LDA + kt * 32 + quad * 8];
            #pragma unroll
            for (int nt = 0; nt < 8; ++nt) {
                bf16x8 bf = *(bf16x8*)&Bs[(nt * 16 + l15) * LDA + kt * 32 + quad * 8];
                acc[nt] = __builtin_amdgcn_mfma_f32_16x16x32_bf16(af, bf, acc[nt], 0, 0, 0);
            }
        }
        // epilogue: e+b2 back into own wave's A rows (wave w only reads/writes rows w*16..+15)
        #pragma unroll
        for (int nt = 0; nt < 8; ++nt) {
            int col = nt * 16 + l15;
            float b2c = b2[col];
            #pragma unroll
            for (int r = 0; r < 4; ++r) {
                int row = w * 16 + quad * 4 + r;
                As[row * LDA + col] = f2bf(acc[nt][r] + b2c);
            }
        }
        __syncthreads();
        #pragma unroll
        for (int kk = 0; kk < 4; ++kk) {
            int i = tid + kk * 256;
            int row = (i * 8) >> 7, col = (i * 8) & 127;
            int gr = base + row;
            if (gr < e1)
                *(bf16x8*)&emsg[(size_t)(gr - e0) * 128 + col] = *(bf16x8*)&As[row * LDA + col];
        }
    }
}

// ---------------- gather chunk [e0,e1): a0[n] += sum relu(h[src]+emsg)*w ----------------
__global__ __launch_bounds__(256) void k_gather(
    const unsigned short* __restrict__ h, const int* __restrict__ offs,
    const int2* __restrict__ pmeta, const unsigned short* __restrict__ emsg,
    unsigned short* __restrict__ a0, int e0, int e1, int N)
{
    int grp = threadIdx.x >> 5, lane = threadIdx.x & 31;
    int n = blockIdx.x * 8 + grp;
    if (n >= N) return;
    int k0 = offs[n], k1 = offs[n + 1];
    int lo = max(k0, e0), hi = min(k1, e1);
    if (lo >= hi) return;
    float m0 = 0.f, m1 = 0.f, m2 = 0.f, m3 = 0.f;
    for (int k = lo; k < hi; ++k) {
        int2 mt = pmeta[k];
        float w = __int_as_float(mt.y);
        ushort4 ev = *(const ushort4*)&emsg[(size_t)(k - e0) * 128 + lane * 4];
        ushort4 hv = *(const ushort4*)&h[(size_t)mt.x * 128 + lane * 4];
        m0 += fmaxf(bf2f(hv.x) + bf2f(ev.x), 0.f) * w;
        m1 += fmaxf(bf2f(hv.y) + bf2f(ev.y), 0.f) * w;
        m2 += fmaxf(bf2f(hv.z) + bf2f(ev.z), 0.f) * w;
        m3 += fmaxf(bf2f(hv.w) + bf2f(ev.w), 0.f) * w;
    }
    ushort4 cur = *(ushort4*)&a0[(size_t)n * 128 + lane * 4];
    ushort4 o;
    o.x = f2bfu(bf2f(cur.x) + m0);
    o.y = f2bfu(bf2f(cur.y) + m1);
    o.z = f2bfu(bf2f(cur.z) + m2);
    o.w = f2bfu(bf2f(cur.w) + m3);
    *(ushort4*)&a0[(size_t)n * 128 + lane * 4] = o;
}

// ---------------- layer-1 edge MLP (d=28, f32, sorted, unchunked) ----------------
__global__ __launch_bounds__(256) void k_emsg28(
    const int* __restrict__ perm, const float4* __restrict__ ea4,
    const float* __restrict__ W1, const float* __restrict__ b1,
    const float* __restrict__ W2, const float* __restrict__ b2,
    unsigned short* __restrict__ emsg28, int E)
{
    __shared__ float W1s[4*28], W2s[28*28], b1s[28], b2s[28];
    __shared__ float tbuf[8][28];
    int tid = threadIdx.x;
    for (int i = tid; i < 4*28; i += 256) W1s[i] = W1[i];
    for (int i = tid; i < 28*28; i += 256) W2s[i] = W2[i];
    if (tid < 28) { b1s[tid] = b1[tid]; b2s[tid] = b2[tid]; }
    __syncthreads();
    int sub = tid >> 5, j = tid & 31;
    int numGroups = (E + 7) >> 3;
    for (int gb = blockIdx.x; gb < numGroups; gb += gridDim.x) {
        int k = gb * 8 + sub;
        bool valid = (k < E);
        float4 a = valid ? ea4[perm[k]] : make_float4(0.f, 0.f, 0.f, 0.f);
        if (j < 28) {
            float t = a.x*W1s[j] + a.y*W1s[28+j] + a.z*W1s[56+j] + a.w*W1s[84+j] + b1s[j];
            tbuf[sub][j] = fmaxf(t, 0.f);
        }
        __syncthreads();
        if (valid && j < 28) {
            float acc = b2s[j];
            #pragma unroll
            for (int i = 0; i < 28; ++i) acc = fmaf(tbuf[sub][i], W2s[i*28 + j], acc);
            emsg28[(size_t)k * 28 + j] = f2bfu(acc);
        }
        __syncthreads();
    }
}

// ---------------- gather (d=28): u28 = (1+eps1)x[n] + sum relu(x[src]+e)*w ----------------
__global__ __launch_bounds__(256) void k_gather28(
    const float* __restrict__ x, const int* __restrict__ offs,
    const int2* __restrict__ pmeta, const unsigned short* __restrict__ emsg28,
    const float* __restrict__ eps1, float* __restrict__ u28, int N)
{
    int grp = threadIdx.x >> 5, lane = threadIdx.x & 31;
    int n = blockIdx.x * 8 + grp;
    if (n >= N || lane >= 28) return;
    float s = 1.0f + eps1[0];
    int k0 = offs[n], k1 = offs[n + 1];
    float m = 0.f;
    for (int k = k0; k < k1; ++k) {
        int2 mt = pmeta[k];
        float w = __int_as_float(mt.y);
        float e = bf2f(emsg28[(size_t)k * 28 + lane]);
        m += fmaxf(x[(size_t)mt.x * 28 + lane] + e, 0.f) * w;
    }
    u28[(size_t)n * 28 + lane] = fmaf(s, x[(size_t)n * 28 + lane], m);
}

// ---------------- layer-1 first linear: t = relu(u28 @ W[28,128] + b) -> bf16 ----------------
__global__ __launch_bounds__(256) void k_lin_s(
    const float* __restrict__ src, const float* __restrict__ W,
    const float* __restrict__ b, unsigned short* __restrict__ dst, int N)
{
    __shared__ float Ws[28*128];
    __shared__ float ub[8][28];
    int tid = threadIdx.x;
    for (int i = tid; i < 28*128; i += 256) Ws[i] = W[i];
    __syncthreads();
    int j = tid & 127, g = tid >> 7;
    float bj = b[j];
    int numGroups = (N + 7) >> 3;
    for (int gb = blockIdx.x; gb < numGroups; gb += gridDim.x) {
        int base = gb * 8;
        __syncthreads();
        for (int k = tid; k < 8*28; k += 256) {
            int r = k / 28, c = k - r*28;
            int rr = base + r;
            ub[r][c] = (rr < N) ? src[(size_t)rr*28 + c] : 0.f;
        }
        __syncthreads();
        float a0 = bj, a1 = bj, a2 = bj, a3 = bj;
        const float* u0 = ub[g*4+0]; const float* u1 = ub[g*4+1];
        const float* u2 = ub[g*4+2]; const float* u3 = ub[g*4+3];
        #pragma unroll
        for (int i = 0; i < 28; ++i) {
            float w = Ws[i*128 + j];
            a0 = fmaf(u0[i], w, a0); a1 = fmaf(u1[i], w, a1);
            a2 = fmaf(u2[i], w, a2); a3 = fmaf(u3[i], w, a3);
        }
        int r0 = base + g*4;
        if (r0 + 0 < N) dst[(size_t)(r0+0)*128 + j] = f2bfu(fmaxf(a0, 0.f));
        if (r0 + 1 < N) dst[(size_t)(r0+1)*128 + j] = f2bfu(fmaxf(a1, 0.f));
        if (r0 + 2 < N) dst[(size_t)(r0+2)*128 + j] = f2bfu(fmaxf(a2, 0.f));
        if (r0 + 3 < N) dst[(size_t)(r0+3)*128 + j] = f2bfu(fmaxf(a3, 0.f));
    }
}

// ---------------- MFMA node GEMM (bf16 in/out, in-place safe) ----------------
// dstT non-null: relu->bf16. Else dstZ: raw bf16 + f32 BN stats (from pre-rounded acc).
__global__ __launch_bounds__(256) void k_mm(
    const unsigned short* __restrict__ src, const short* __restrict__ Wt,
    const float* __restrict__ bias, unsigned short* __restrict__ dstT,
    unsigned short* __restrict__ dstZ, float* __restrict__ stats, int N)
{
    __shared__ short Bs[128 * LDA];
    __shared__ short As[64 * LDA];
    __shared__ float sstat[256];
    int tid = threadIdx.x;
    for (int i = tid; i < 2048; i += 256) {
        int n = (i * 8) >> 7, k = (i * 8) & 127;
        *(bf16x8*)&Bs[n * LDA + k] = *(const bf16x8*)&Wt[i * 8];
    }
    sstat[tid] = 0.f;
    __syncthreads();
    int w = tid >> 6, lane = tid & 63;
    int l15 = lane & 15, quad = lane >> 4;
    float lsum[8], lsq[8];
    #pragma unroll
    for (int nt = 0; nt < 8; ++nt) { lsum[nt] = 0.f; lsq[nt] = 0.f; }

    int numTiles = (N + 63) >> 6;
    for (int tile = blockIdx.x; tile < numTiles; tile += gridDim.x) {
        int base = tile * 64;
        __syncthreads();
        #pragma unroll
        for (int kk = 0; kk < 4; ++kk) {
            int i = tid + kk * 256;
            int row = (i * 8) >> 7, col = (i * 8) & 127;
            int rr = base + row;
            bf16x8 v;
            if (rr < N) v = *(const bf16x8*)&src[(size_t)rr * 128 + col];
            else        v = (bf16x8){0,0,0,0,0,0,0,0};
            *(bf16x8*)&As[row * LDA + col] = v;
        }
        __syncthreads();
        f32x4 acc[8];
        #pragma unroll
        for (int nt = 0; nt < 8; ++nt) acc[nt] = (f32x4){0.f, 0.f, 0.f, 0.f};
        #pragma unroll
        for (int kt = 0; kt < 4; ++kt) {
            bf16x8 af = *(bf16x8*)&As[(w * 16 + l15) * LDA + kt * 32 + quad * 8];
            #pragma unroll
            for (int nt = 0; nt < 8; ++nt) {
                bf16x8 bf = *(bf16x8*)&Bs[(nt * 16 + l15) * LDA + kt * 32 + quad * 8];
                acc[nt] = __builtin_amdgcn_mfma_f32_16x16x32_bf16(af, bf, acc[nt], 0, 0, 0);
            }
        }
        int row0 = base + w * 16 + quad * 4;
        #pragma unroll
        for (int nt = 0; nt < 8; ++nt) {
            int col = nt * 16 + l15;
            float bc = bias[col];
            #pragma unroll
            for (int r = 0; r < 4; ++r) {
                int row = row0 + r;
                if (row < N) {
                    float z = acc[nt][r] + bc;
                    if (dstT) {
                        dstT[(size_t)row * 128 + col] = f2bfu(fmaxf(z, 0.f));
                    } else {
                        dstZ[(size_t)row * 128 + col] = f2bfu(z);
                        lsum[nt] += z; lsq[nt] = fmaf(z, z, lsq[nt]);
                    }
                }
            }
        }
    }
    if (stats) {
        #pragma unroll
        for (int nt = 0; nt < 8; ++nt) {
            int col = nt * 16 + l15;
            atomicAdd(&sstat[col], lsum[nt]);
            atomicAdd(&sstat[128 + col], lsq[nt]);
        }
        __syncthreads();
        atomicAdd(&stats[tid], sstat[tid]);
    }
}

// ---------------- BN(train)+relu(+residual); writes h bf16, optional a0-init or fused pool ----------------
// z bf16 (may be same buffer as uout a0 — same-index read-then-write).
__global__ __launch_bounds__(256) void k_bn(
    const unsigned short* __restrict__ z, const float* __restrict__ stats,
    const float* __restrict__ g, const float* __restrict__ b,
    unsigned short* __restrict__ h, unsigned short* __restrict__ uout,
    const float* __restrict__ epsp, int epsIdx,
    const float* __restrict__ mask, const int* __restrict__ s2n,
    float* __restrict__ pout,
    int N, int residual, float invN)
{
    float s = uout ? (1.0f + epsp[epsIdx]) : 0.f;
    int total4 = N * 32;
    for (int idx4 = blockIdx.x * 256 + threadIdx.x; idx4 < total4; idx4 += gridDim.x * 256) {
        int n = idx4 >> 5, c0 = (idx4 & 31) * 4;
        ushort4 z4 = *(const ushort4*)&z[(size_t)n * 128 + c0];
        float zv[4] = { bf2f(z4.x), bf2f(z4.y), bf2f(z4.z), bf2f(z4.w) };
        float hn[4];
        #pragma unroll
        for (int r = 0; r < 4; ++r) {
            int col = c0 + r;
            float mu  = stats[col] * invN;
            float var = fmaf(stats[128 + col], invN, -mu * mu);
            float sc  = rsqrtf(fmaxf(var, 0.f) + BNEPS) * g[col];
            hn[r] = fmaxf(fmaf(zv[r] - mu, sc, b[col]), 0.f);
        }
        if (residual) {
            ushort4 h4 = *(const ushort4*)&h[(size_t)n * 128 + c0];
            hn[0] += bf2f(h4.x); hn[1] += bf2f(h4.y);
            hn[2] += bf2f(h4.z); hn[3] += bf2f(h4.w);
        }
        if (pout) {
            float mk = mask[n];
            if (mk != 0.f) {
                float* po = &pout[(size_t)s2n[n] * 128 + c0];
                #pragma unroll
                for (int r = 0; r < 4; ++r) atomicAdd(&po[r], hn[r] * mk);
            }
        } else {
            ushort4 o;
            o.x = f2bfu(hn[0]); o.y = f2bfu(hn[1]);
            o.z = f2bfu(hn[2]); o.w = f2bfu(hn[3]);
            *(ushort4*)&h[(size_t)n * 128 + c0] = o;
            if (uout) {
                ushort4 u;
                u.x = f2bfu(s * hn[0]); u.y = f2bfu(s * hn[1]);
                u.z = f2bfu(s * hn[2]); u.w = f2bfu(s * hn[3]);
                *(ushort4*)&uout[(size_t)n * 128 + c0] = u;
            }
        }
    }
}

extern "C" void kernel_launch(void* const* d_in, const int* in_sizes, int n_in,
                              void* d_out, int out_size, void* d_ws, size_t ws_size,
                              hipStream_t stream) {
    const float* x    = (const float*)d_in[0];
    const int*   ei   = (const int*)d_in[1];
    const float* ea   = (const float*)d_in[2];
    const float* ew   = (const float*)d_in[3];
    const float* mask = (const float*)d_in[4];
    const int*   s2n  = (const int*)d_in[5];
    const float* be1W1 = (const float*)d_in[6];
    const float* be1b1 = (const float*)d_in[7];
    const float* be1W2 = (const float*)d_in[8];
    const float* be1b2 = (const float*)d_in[9];
    const float* m1W1  = (const float*)d_in[10];
    const float* m1b1  = (const float*)d_in[11];
    const float* m1W2  = (const float*)d_in[12];
    const float* m1b2  = (const float*)d_in[13];
    const float* bn1g  = (const float*)d_in[14];
    const float* bn1b  = (const float*)d_in[15];
    const float* eps1  = (const float*)d_in[16];
    const float* beW1  = (const float*)d_in[17];
    const float* beb1  = (const float*)d_in[18];
    const float* beW2  = (const float*)d_in[19];
    const float* beb2  = (const float*)d_in[20];
    const float* mW1   = (const float*)d_in[21];
    const float* mb1   = (const float*)d_in[22];
    const float* mW2   = (const float*)d_in[23];
    const float* mb2   = (const float*)d_in[24];
    const float* bng   = (const float*)d_in[25];
    const float* bnb   = (const float*)d_in[26];
    const float* epsL  = (const float*)d_in[27];

    const int N = in_sizes[0] / 28;
    const int E = in_sizes[1] / 2;
    const int S = out_size / 128;
    const float invN = 1.0f / (float)N;
    const int EC = (E + 1) / 2;   // edge chunk size (2 chunks)

    // ---- workspace layout (16B-aligned blocks), total ~189 MB ----
    auto al16 = [](size_t v) { return (v + 15) & ~(size_t)15; };
    char* ws = (char*)d_ws;
    size_t offH      = 0;                                    // h bf16 N*128
    size_t offA0     = al16(offH + (size_t)N * 256);         // a0 bf16 N*128 (u/t/z)
    size_t offEm     = al16(offA0 + (size_t)N * 256);        // emsg bf16 EC*128 (L1: E*28)
    size_t emBytes   = (size_t)EC * 256;
    if ((size_t)E * 56 > emBytes) emBytes = (size_t)E * 56;
    size_t offStats  = al16(offEm + emBytes);                // 4*256 f32
    size_t offWts    = al16(offStats + 4096);                // 10*16384 bf16
    size_t offCounts = al16(offWts + 10 * 16384 * 2);
    size_t offOffs   = al16(offCounts + (size_t)N * 4);
    size_t offCursor = al16(offOffs + (size_t)(N + 1) * 4);
    size_t offPerm   = al16(offCursor + (size_t)N * 4);
    size_t offPmeta  = al16(offPerm + (size_t)E * 4);
    size_t need      = offPmeta + (size_t)E * 8;
    if (ws_size < need) return;   // ~189MB — under the proven 205MB floor

    unsigned short* h    = (unsigned short*)(ws + offH);
    unsigned short* a0   = (unsigned short*)(ws + offA0);
    unsigned short* emsg = (unsigned short*)(ws + offEm);
    float* u28    = (float*)(ws + offA0);       // layer-1: f32 N*28 inside a0
    float* stats  = (float*)(ws + offStats);
    short* wts    = (short*)(ws + offWts);
    int*   counts = (int*)(ws + offCounts);
    int*   offs   = (int*)(ws + offOffs);
    int*   cursor = (int*)(ws + offCursor);
    int*   perm   = (int*)(ws + offPerm);
    int2*  pmeta  = (int2*)(ws + offPmeta);
    const float4* ea4 = (const float4*)ea;

    hipMemsetAsync(stats, 0, 4 * 256 * sizeof(float), stream);
    hipMemsetAsync(counts, 0, (size_t)N * sizeof(int), stream);
    hipMemsetAsync(d_out, 0, (size_t)S * 128 * sizeof(float), stream);

    k_prep<<<40, 256, 0, stream>>>(m1W2, beW2, mW1, mW2, wts);

    // ---- CSR (dst-sorted edges) ----
    k_count<<<1024, 256, 0, stream>>>(ei, counts, E);
    k_scan<<<1, 1024, 0, stream>>>(counts, offs, cursor, N);
    k_scatter<<<1024, 256, 0, stream>>>(ei, ew, cursor, perm, pmeta, E);

    const short* wt_m1W2 = wts;
    auto wt_be = [&](int l) { return wts + (size_t)(1 + 3 * l + 0) * 16384; };
    auto wt_m1 = [&](int l) { return wts + (size_t)(1 + 3 * l + 1) * 16384; };
    auto wt_m2 = [&](int l) { return wts + (size_t)(1 + 3 * l + 2) * 16384; };

    int gatherBlocks = (N + 7) / 8;

    // ---- layer 1 (28 -> 128): emsg28 full, u28 f32 in a0, t bf16 in h-buf ----
    k_emsg28<<<2048, 256, 0, stream>>>(perm, ea4, be1W1, be1b1, be1W2, be1b2, emsg, E);
    k_gather28<<<gatherBlocks, 256, 0, stream>>>(x, offs, pmeta, emsg, eps1, u28, N);
    k_lin_s<<<1024, 256, 0, stream>>>(u28, m1W1, m1b1, h, N);
    k_mm<<<1024, 256, 0, stream>>>(h, wt_m1W2, m1b2, nullptr, a0, stats, N);
    k_bn<<<2048, 256, 0, stream>>>(a0, stats, bn1g, bn1b, h, a0, epsL, 0,
                                   nullptr, nullptr, nullptr, N, 0, invN);

    // ---- layers 2..4: a0 pre-init'd to (1+eps)h by previous k_bn ----
    for (int l = 0; l < 3; ++l) {
        for (int c = 0; c < 2; ++c) {
            int e0 = c * EC, e1 = min(e0 + EC, E);
            k_emsg<<<2048, 256, 0, stream>>>(perm, ea4,
                beW1 + (size_t)l * 512, beb1 + (size_t)l * 128,
                wt_be(l), beb2 + (size_t)l * 128, emsg, e0, e1);
            k_gather<<<gatherBlocks, 256, 0, stream>>>(h, offs, pmeta, emsg, a0, e0, e1, N);
        }
        k_mm<<<1024, 256, 0, stream>>>(a0, wt_m1(l), mb1 + (size_t)l * 128,
                                       a0, nullptr, nullptr, N);
        k_mm<<<1024, 256, 0, stream>>>(a0, wt_m2(l), mb2 + (size_t)l * 128,
                                       nullptr, a0, stats + 256 * (l + 1), N);
        if (l < 2) {
            k_bn<<<2048, 256, 0, stream>>>(a0, stats + 256 * (l + 1),
                bng + (size_t)l * 128, bnb + (size_t)l * 128,
                h, a0, epsL, l + 1, nullptr, nullptr, nullptr, N, 1, invN);
        } else {
            k_bn<<<2048, 256, 0, stream>>>(a0, stats + 256 * (l + 1),
                bng + (size_t)l * 128, bnb + (size_t)l * 128,
                h, nullptr, epsL, 0, mask, s2n, (float*)d_out, N, 1, invN);
        }
    }
}

// Round 6
// 1463.484 us; speedup vs baseline: 1.2931x; 1.2931x over previous
//
#include <hip/hip_runtime.h>
#include <hip/hip_bf16.h>

// ZINC GINE inner, round 6: round-5 CSR design + parallel 3-phase scan
// (round-5's single-block k_scan was 460us = 24% of runtime).

#define BNEPS 1e-5f
#define LDA 136   // 128 + 8 shorts pad
#define SCAN_NB 240

typedef __attribute__((ext_vector_type(8))) short bf16x8;
typedef __attribute__((ext_vector_type(4))) float f32x4;

__device__ inline short f2bf(float f) {
    __hip_bfloat16 h = __float2bfloat16(f);
    return *reinterpret_cast<short*>(&h);
}
__device__ inline unsigned short f2bfu(float f) {
    __hip_bfloat16 h = __float2bfloat16(f);
    return *reinterpret_cast<unsigned short*>(&h);
}
__device__ inline float bf2f(unsigned short u) {
    union { unsigned int i; float f; } v; v.i = ((unsigned int)u) << 16; return v.f;
}

// ---------------- prep: transpose 10 f32 [128,128] weights -> bf16 W^T ----------------
__global__ __launch_bounds__(256) void k_prep(
    const float* __restrict__ m1W2, const float* __restrict__ beW2,
    const float* __restrict__ mW1, const float* __restrict__ mW2,
    short* __restrict__ out)
{
    __shared__ float tileS[64][65];
    int b = blockIdx.x, mat = b >> 2, t = b & 3;
    const float* Wsrc;
    if (mat == 0) Wsrc = m1W2;
    else {
        int l = (mat - 1) / 3, which = (mat - 1) % 3;
        Wsrc = (which == 0) ? beW2 + (size_t)l * 16384
             : (which == 1) ? mW1 + (size_t)l * 16384
             :                mW2 + (size_t)l * 16384;
    }
    short* dst = out + (size_t)mat * 16384;
    int tr = (t >> 1) * 64, tc = (t & 1) * 64;
    for (int i = threadIdx.x; i < 4096; i += 256) {
        int r = i >> 6, c = i & 63;
        tileS[r][c] = Wsrc[(size_t)(tr + r) * 128 + (tc + c)];
    }
    __syncthreads();
    for (int i = threadIdx.x; i < 4096; i += 256) {
        int n = i >> 6, k = i & 63;
        dst[(size_t)(tc + n) * 128 + (tr + k)] = f2bf(tileS[k][n]);
    }
}

// ---------------- CSR build ----------------
__global__ __launch_bounds__(256) void k_count(
    const int* __restrict__ ei, int* __restrict__ counts, int E)
{
    for (int e = blockIdx.x * 256 + threadIdx.x; e < E; e += gridDim.x * 256)
        atomicAdd(&counts[ei[E + e]], 1);
}

// phase A: per-block segment sums (coalesced)
__global__ __launch_bounds__(256) void k_scanA(
    const int* __restrict__ counts, int* __restrict__ bsum, int N, int seg)
{
    __shared__ int red[256];
    int b = blockIdx.x;
    int lo = b * seg, hi = min(lo + seg, N);
    int s = 0;
    for (int i = lo + threadIdx.x; i < hi; i += 256) s += counts[i];
    red[threadIdx.x] = s;
    __syncthreads();
    for (int d = 128; d > 0; d >>= 1) {
        if (threadIdx.x < d) red[threadIdx.x] += red[threadIdx.x + d];
        __syncthreads();
    }
    if (threadIdx.x == 0) bsum[b] = red[0];
}

// phase B: exclusive scan of block sums; also writes offs[N]=E
__global__ __launch_bounds__(256) void k_scanB(
    int* __restrict__ bsum, int nb, int* __restrict__ offs, int N, int E)
{
    __shared__ int sh[256];
    int v = (threadIdx.x < nb) ? bsum[threadIdx.x] : 0;
    sh[threadIdx.x] = v;
    __syncthreads();
    for (int d = 1; d < 256; d <<= 1) {
        int t = (threadIdx.x >= d) ? sh[threadIdx.x - d] : 0;
        __syncthreads();
        sh[threadIdx.x] += t;
        __syncthreads();
    }
    if (threadIdx.x < nb) bsum[threadIdx.x] = sh[threadIdx.x] - v;  // exclusive
    if (threadIdx.x == 0) offs[N] = E;
}

// phase C: per-segment tile-wise exclusive scan -> offs & cursor
__global__ __launch_bounds__(256) void k_scanC(
    const int* __restrict__ counts, const int* __restrict__ bsum,
    int* __restrict__ offs, int* __restrict__ cursor, int N, int seg)
{
    __shared__ int sh[256];
    int b = blockIdx.x;
    int lo = b * seg, hi = min(lo + seg, N);
    int base = bsum[b];
    for (int t0 = lo; t0 < hi; t0 += 256) {
        int i = t0 + threadIdx.x;
        int v = (i < hi) ? counts[i] : 0;
        sh[threadIdx.x] = v;
        __syncthreads();
        for (int d = 1; d < 256; d <<= 1) {
            int t = (threadIdx.x >= d) ? sh[threadIdx.x - d] : 0;
            __syncthreads();
            sh[threadIdx.x] += t;
            __syncthreads();
        }
        int excl = base + sh[threadIdx.x] - v;
        if (i < hi) { offs[i] = excl; cursor[i] = excl; }
        int tileTotal = sh[255];
        __syncthreads();
        base += tileTotal;
    }
}

__global__ __launch_bounds__(256) void k_scatter(
    const int* __restrict__ ei, const float* __restrict__ ew,
    int* __restrict__ cursor, int* __restrict__ perm, int2* __restrict__ pmeta, int E)
{
    for (int e = blockIdx.x * 256 + threadIdx.x; e < E; e += gridDim.x * 256) {
        int d = ei[E + e];
        int pos = atomicAdd(&cursor[d], 1);
        perm[pos] = e;
        pmeta[pos] = make_int2(ei[e], __float_as_int(ew[e]));
    }
}

// ---------------- hidden edge GEMM over sorted chunk [e0,e1) ----------------
__global__ __launch_bounds__(256) void k_emsg(
    const int* __restrict__ perm, const float4* __restrict__ ea4,
    const float* __restrict__ W1, const float* __restrict__ b1,
    const short* __restrict__ W2t, const float* __restrict__ b2,
    unsigned short* __restrict__ emsg, int e0, int e1)
{
    __shared__ short Bs[128 * LDA];
    __shared__ short As[64 * LDA];
    __shared__ float eas[64][4];
    int tid = threadIdx.x;
    for (int i = tid; i < 2048; i += 256) {
        int n = (i * 8) >> 7, k = (i * 8) & 127;
        *(bf16x8*)&Bs[n * LDA + k] = *(const bf16x8*)&W2t[i * 8];
    }
    int j = tid & 127, half = tid >> 7;
    float w10 = W1[j], w11 = W1[128 + j], w12 = W1[256 + j], w13 = W1[384 + j];
    float b1j = b1[j];
    int w = tid >> 6, lane = tid & 63;
    int l15 = lane & 15, quad = lane >> 4;
    __syncthreads();

    int numTiles = (e1 - e0 + 63) >> 6;
    for (int tile = blockIdx.x; tile < numTiles; tile += gridDim.x) {
        int base = e0 + tile * 64;
        __syncthreads();
        if (tid < 64) {
            int k = base + tid;
            float4 a = make_float4(0.f, 0.f, 0.f, 0.f);
            if (k < e1) a = ea4[perm[k]];
            eas[tid][0] = a.x; eas[tid][1] = a.y; eas[tid][2] = a.z; eas[tid][3] = a.w;
        }
        __syncthreads();
        #pragma unroll
        for (int q = 0; q < 32; ++q) {
            int e = half * 32 + q;
            float t = fmaf(eas[e][0], w10, fmaf(eas[e][1], w11,
                      fmaf(eas[e][2], w12, fmaf(eas[e][3], w13, b1j))));
            As[e * LDA + j] = f2bf(fmaxf(t, 0.f));
        }
        __syncthreads();
        f32x4 acc[8];
        #pragma unroll
        for (int nt = 0; nt < 8; ++nt) acc[nt] = (f32x4){0.f, 0.f, 0.f, 0.f};
        #pragma unroll
        for (int kt = 0; kt < 4; ++kt) {
            bf16x8 af = *(bf16x8*)&As[(w * 16 + l15) * LDA + kt * 32 + quad * 8];
            #pragma unroll
            for (int nt = 0; nt < 8; ++nt) {
                bf16x8 bf = *(bf16x8*)&Bs[(nt * 16 + l15) * LDA + kt * 32 + quad * 8];
                acc[nt] = __builtin_amdgcn_mfma_f32_16x16x32_bf16(af, bf, acc[nt], 0, 0, 0);
            }
        }
        #pragma unroll
        for (int nt = 0; nt < 8; ++nt) {
            int col = nt * 16 + l15;
            float b2c = b2[col];
            #pragma unroll
            for (int r = 0; r < 4; ++r) {
                int row = w * 16 + quad * 4 + r;
                As[row * LDA + col] = f2bf(acc[nt][r] + b2c);
            }
        }
        __syncthreads();
        #pragma unroll
        for (int kk = 0; kk < 4; ++kk) {
            int i = tid + kk * 256;
            int row = (i * 8) >> 7, col = (i * 8) & 127;
            int gr = base + row;
            if (gr < e1)
                *(bf16x8*)&emsg[(size_t)(gr - e0) * 128 + col] = *(bf16x8*)&As[row * LDA + col];
        }
    }
}

// ---------------- gather chunk [e0,e1): a0[n] += sum relu(h[src]+emsg)*w ----------------
__global__ __launch_bounds__(256) void k_gather(
    const unsigned short* __restrict__ h, const int* __restrict__ offs,
    const int2* __restrict__ pmeta, const unsigned short* __restrict__ emsg,
    unsigned short* __restrict__ a0, int e0, int e1, int N)
{
    int grp = threadIdx.x >> 5, lane = threadIdx.x & 31;
    int n = blockIdx.x * 8 + grp;
    if (n >= N) return;
    int k0 = offs[n], k1 = offs[n + 1];
    int lo = max(k0, e0), hi = min(k1, e1);
    if (lo >= hi) return;
    float m0 = 0.f, m1 = 0.f, m2 = 0.f, m3 = 0.f;
    for (int k = lo; k < hi; ++k) {
        int2 mt = pmeta[k];
        float w = __int_as_float(mt.y);
        ushort4 ev = *(const ushort4*)&emsg[(size_t)(k - e0) * 128 + lane * 4];
        ushort4 hv = *(const ushort4*)&h[(size_t)mt.x * 128 + lane * 4];
        m0 += fmaxf(bf2f(hv.x) + bf2f(ev.x), 0.f) * w;
        m1 += fmaxf(bf2f(hv.y) + bf2f(ev.y), 0.f) * w;
        m2 += fmaxf(bf2f(hv.z) + bf2f(ev.z), 0.f) * w;
        m3 += fmaxf(bf2f(hv.w) + bf2f(ev.w), 0.f) * w;
    }
    ushort4 cur = *(ushort4*)&a0[(size_t)n * 128 + lane * 4];
    ushort4 o;
    o.x = f2bfu(bf2f(cur.x) + m0);
    o.y = f2bfu(bf2f(cur.y) + m1);
    o.z = f2bfu(bf2f(cur.z) + m2);
    o.w = f2bfu(bf2f(cur.w) + m3);
    *(ushort4*)&a0[(size_t)n * 128 + lane * 4] = o;
}

// ---------------- layer-1 edge MLP (d=28) ----------------
__global__ __launch_bounds__(256) void k_emsg28(
    const int* __restrict__ perm, const float4* __restrict__ ea4,
    const float* __restrict__ W1, const float* __restrict__ b1,
    const float* __restrict__ W2, const float* __restrict__ b2,
    unsigned short* __restrict__ emsg28, int E)
{
    __shared__ float W1s[4*28], W2s[28*28], b1s[28], b2s[28];
    __shared__ float tbuf[8][28];
    int tid = threadIdx.x;
    for (int i = tid; i < 4*28; i += 256) W1s[i] = W1[i];
    for (int i = tid; i < 28*28; i += 256) W2s[i] = W2[i];
    if (tid < 28) { b1s[tid] = b1[tid]; b2s[tid] = b2[tid]; }
    __syncthreads();
    int sub = tid >> 5, j = tid & 31;
    int numGroups = (E + 7) >> 3;
    for (int gb = blockIdx.x; gb < numGroups; gb += gridDim.x) {
        int k = gb * 8 + sub;
        bool valid = (k < E);
        float4 a = valid ? ea4[perm[k]] : make_float4(0.f, 0.f, 0.f, 0.f);
        if (j < 28) {
            float t = a.x*W1s[j] + a.y*W1s[28+j] + a.z*W1s[56+j] + a.w*W1s[84+j] + b1s[j];
            tbuf[sub][j] = fmaxf(t, 0.f);
        }
        __syncthreads();
        if (valid && j < 28) {
            float acc = b2s[j];
            #pragma unroll
            for (int i = 0; i < 28; ++i) acc = fmaf(tbuf[sub][i], W2s[i*28 + j], acc);
            emsg28[(size_t)k * 28 + j] = f2bfu(acc);
        }
        __syncthreads();
    }
}

// ---------------- gather (d=28) ----------------
__global__ __launch_bounds__(256) void k_gather28(
    const float* __restrict__ x, const int* __restrict__ offs,
    const int2* __restrict__ pmeta, const unsigned short* __restrict__ emsg28,
    const float* __restrict__ eps1, float* __restrict__ u28, int N)
{
    int grp = threadIdx.x >> 5, lane = threadIdx.x & 31;
    int n = blockIdx.x * 8 + grp;
    if (n >= N || lane >= 28) return;
    float s = 1.0f + eps1[0];
    int k0 = offs[n], k1 = offs[n + 1];
    float m = 0.f;
    for (int k = k0; k < k1; ++k) {
        int2 mt = pmeta[k];
        float w = __int_as_float(mt.y);
        float e = bf2f(emsg28[(size_t)k * 28 + lane]);
        m += fmaxf(x[(size_t)mt.x * 28 + lane] + e, 0.f) * w;
    }
    u28[(size_t)n * 28 + lane] = fmaf(s, x[(size_t)n * 28 + lane], m);
}

// ---------------- layer-1 first linear ----------------
__global__ __launch_bounds__(256) void k_lin_s(
    const float* __restrict__ src, const float* __restrict__ W,
    const float* __restrict__ b, unsigned short* __restrict__ dst, int N)
{
    __shared__ float Ws[28*128];
    __shared__ float ub[8][28];
    int tid = threadIdx.x;
    for (int i = tid; i < 28*128; i += 256) Ws[i] = W[i];
    __syncthreads();
    int j = tid & 127, g = tid >> 7;
    float bj = b[j];
    int numGroups = (N + 7) >> 3;
    for (int gb = blockIdx.x; gb < numGroups; gb += gridDim.x) {
        int base = gb * 8;
        __syncthreads();
        for (int k = tid; k < 8*28; k += 256) {
            int r = k / 28, c = k - r*28;
            int rr = base + r;
            ub[r][c] = (rr < N) ? src[(size_t)rr*28 + c] : 0.f;
        }
        __syncthreads();
        float a0 = bj, a1 = bj, a2 = bj, a3 = bj;
        const float* u0 = ub[g*4+0]; const float* u1 = ub[g*4+1];
        const float* u2 = ub[g*4+2]; const float* u3 = ub[g*4+3];
        #pragma unroll
        for (int i = 0; i < 28; ++i) {
            float w = Ws[i*128 + j];
            a0 = fmaf(u0[i], w, a0); a1 = fmaf(u1[i], w, a1);
            a2 = fmaf(u2[i], w, a2); a3 = fmaf(u3[i], w, a3);
        }
        int r0 = base + g*4;
        if (r0 + 0 < N) dst[(size_t)(r0+0)*128 + j] = f2bfu(fmaxf(a0, 0.f));
        if (r0 + 1 < N) dst[(size_t)(r0+1)*128 + j] = f2bfu(fmaxf(a1, 0.f));
        if (r0 + 2 < N) dst[(size_t)(r0+2)*128 + j] = f2bfu(fmaxf(a2, 0.f));
        if (r0 + 3 < N) dst[(size_t)(r0+3)*128 + j] = f2bfu(fmaxf(a3, 0.f));
    }
}

// ---------------- MFMA node GEMM (bf16 in/out, in-place safe) ----------------
__global__ __launch_bounds__(256) void k_mm(
    const unsigned short* __restrict__ src, const short* __restrict__ Wt,
    const float* __restrict__ bias, unsigned short* __restrict__ dstT,
    unsigned short* __restrict__ dstZ, float* __restrict__ stats, int N)
{
    __shared__ short Bs[128 * LDA];
    __shared__ short As[64 * LDA];
    __shared__ float sstat[256];
    int tid = threadIdx.x;
    for (int i = tid; i < 2048; i += 256) {
        int n = (i * 8) >> 7, k = (i * 8) & 127;
        *(bf16x8*)&Bs[n * LDA + k] = *(const bf16x8*)&Wt[i * 8];
    }
    sstat[tid] = 0.f;
    __syncthreads();
    int w = tid >> 6, lane = tid & 63;
    int l15 = lane & 15, quad = lane >> 4;
    float lsum[8], lsq[8];
    #pragma unroll
    for (int nt = 0; nt < 8; ++nt) { lsum[nt] = 0.f; lsq[nt] = 0.f; }

    int numTiles = (N + 63) >> 6;
    for (int tile = blockIdx.x; tile < numTiles; tile += gridDim.x) {
        int base = tile * 64;
        __syncthreads();
        #pragma unroll
        for (int kk = 0; kk < 4; ++kk) {
            int i = tid + kk * 256;
            int row = (i * 8) >> 7, col = (i * 8) & 127;
            int rr = base + row;
            bf16x8 v;
            if (rr < N) v = *(const bf16x8*)&src[(size_t)rr * 128 + col];
            else        v = (bf16x8){0,0,0,0,0,0,0,0};
            *(bf16x8*)&As[row * LDA + col] = v;
        }
        __syncthreads();
        f32x4 acc[8];
        #pragma unroll
        for (int nt = 0; nt < 8; ++nt) acc[nt] = (f32x4){0.f, 0.f, 0.f, 0.f};
        #pragma unroll
        for (int kt = 0; kt < 4; ++kt) {
            bf16x8 af = *(bf16x8*)&As[(w * 16 + l15) * LDA + kt * 32 + quad * 8];
            #pragma unroll
            for (int nt = 0; nt < 8; ++nt) {
                bf16x8 bf = *(bf16x8*)&Bs[(nt * 16 + l15) * LDA + kt * 32 + quad * 8];
                acc[nt] = __builtin_amdgcn_mfma_f32_16x16x32_bf16(af, bf, acc[nt], 0, 0, 0);
            }
        }
        int row0 = base + w * 16 + quad * 4;
        #pragma unroll
        for (int nt = 0; nt < 8; ++nt) {
            int col = nt * 16 + l15;
            float bc = bias[col];
            #pragma unroll
            for (int r = 0; r < 4; ++r) {
                int row = row0 + r;
                if (row < N) {
                    float z = acc[nt][r] + bc;
                    if (dstT) {
                        dstT[(size_t)row * 128 + col] = f2bfu(fmaxf(z, 0.f));
                    } else {
                        dstZ[(size_t)row * 128 + col] = f2bfu(z);
                        lsum[nt] += z; lsq[nt] = fmaf(z, z, lsq[nt]);
                    }
                }
            }
        }
    }
    if (stats) {
        #pragma unroll
        for (int nt = 0; nt < 8; ++nt) {
            int col = nt * 16 + l15;
            atomicAdd(&sstat[col], lsum[nt]);
            atomicAdd(&sstat[128 + col], lsq[nt]);
        }
        __syncthreads();
        atomicAdd(&stats[tid], sstat[tid]);
    }
}

// ---------------- BN(train)+relu(+residual) ----------------
__global__ __launch_bounds__(256) void k_bn(
    const unsigned short* __restrict__ z, const float* __restrict__ stats,
    const float* __restrict__ g, const float* __restrict__ b,
    unsigned short* __restrict__ h, unsigned short* __restrict__ uout,
    const float* __restrict__ epsp, int epsIdx,
    const float* __restrict__ mask, const int* __restrict__ s2n,
    float* __restrict__ pout,
    int N, int residual, float invN)
{
    float s = uout ? (1.0f + epsp[epsIdx]) : 0.f;
    int total4 = N * 32;
    for (int idx4 = blockIdx.x * 256 + threadIdx.x; idx4 < total4; idx4 += gridDim.x * 256) {
        int n = idx4 >> 5, c0 = (idx4 & 31) * 4;
        ushort4 z4 = *(const ushort4*)&z[(size_t)n * 128 + c0];
        float zv[4] = { bf2f(z4.x), bf2f(z4.y), bf2f(z4.z), bf2f(z4.w) };
        float hn[4];
        #pragma unroll
        for (int r = 0; r < 4; ++r) {
            int col = c0 + r;
            float mu  = stats[col] * invN;
            float var = fmaf(stats[128 + col], invN, -mu * mu);
            float sc  = rsqrtf(fmaxf(var, 0.f) + BNEPS) * g[col];
            hn[r] = fmaxf(fmaf(zv[r] - mu, sc, b[col]), 0.f);
        }
        if (residual) {
            ushort4 h4 = *(const ushort4*)&h[(size_t)n * 128 + c0];
            hn[0] += bf2f(h4.x); hn[1] += bf2f(h4.y);
            hn[2] += bf2f(h4.z); hn[3] += bf2f(h4.w);
        }
        if (pout) {
            float mk = mask[n];
            if (mk != 0.f) {
                float* po = &pout[(size_t)s2n[n] * 128 + c0];
                #pragma unroll
                for (int r = 0; r < 4; ++r) atomicAdd(&po[r], hn[r] * mk);
            }
        } else {
            ushort4 o;
            o.x = f2bfu(hn[0]); o.y = f2bfu(hn[1]);
            o.z = f2bfu(hn[2]); o.w = f2bfu(hn[3]);
            *(ushort4*)&h[(size_t)n * 128 + c0] = o;
            if (uout) {
                ushort4 u;
                u.x = f2bfu(s * hn[0]); u.y = f2bfu(s * hn[1]);
                u.z = f2bfu(s * hn[2]); u.w = f2bfu(s * hn[3]);
                *(ushort4*)&uout[(size_t)n * 128 + c0] = u;
            }
        }
    }
}

extern "C" void kernel_launch(void* const* d_in, const int* in_sizes, int n_in,
                              void* d_out, int out_size, void* d_ws, size_t ws_size,
                              hipStream_t stream) {
    const float* x    = (const float*)d_in[0];
    const int*   ei   = (const int*)d_in[1];
    const float* ea   = (const float*)d_in[2];
    const float* ew   = (const float*)d_in[3];
    const float* mask = (const float*)d_in[4];
    const int*   s2n  = (const int*)d_in[5];
    const float* be1W1 = (const float*)d_in[6];
    const float* be1b1 = (const float*)d_in[7];
    const float* be1W2 = (const float*)d_in[8];
    const float* be1b2 = (const float*)d_in[9];
    const float* m1W1  = (const float*)d_in[10];
    const float* m1b1  = (const float*)d_in[11];
    const float* m1W2  = (const float*)d_in[12];
    const float* m1b2  = (const float*)d_in[13];
    const float* bn1g  = (const float*)d_in[14];
    const float* bn1b  = (const float*)d_in[15];
    const float* eps1  = (const float*)d_in[16];
    const float* beW1  = (const float*)d_in[17];
    const float* beb1  = (const float*)d_in[18];
    const float* beW2  = (const float*)d_in[19];
    const float* beb2  = (const float*)d_in[20];
    const float* mW1   = (const float*)d_in[21];
    const float* mb1   = (const float*)d_in[22];
    const float* mW2   = (const float*)d_in[23];
    const float* mb2   = (const float*)d_in[24];
    const float* bng   = (const float*)d_in[25];
    const float* bnb   = (const float*)d_in[26];
    const float* epsL  = (const float*)d_in[27];

    const int N = in_sizes[0] / 28;
    const int E = in_sizes[1] / 2;
    const int S = out_size / 128;
    const float invN = 1.0f / (float)N;
    const int EC = (E + 1) / 2;

    auto al16 = [](size_t v) { return (v + 15) & ~(size_t)15; };
    char* ws = (char*)d_ws;
    size_t offH      = 0;
    size_t offA0     = al16(offH + (size_t)N * 256);
    size_t offEm     = al16(offA0 + (size_t)N * 256);
    size_t emBytes   = (size_t)EC * 256;
    if ((size_t)E * 56 > emBytes) emBytes = (size_t)E * 56;
    size_t offStats  = al16(offEm + emBytes);
    size_t offWts    = al16(offStats + 4096);
    size_t offCounts = al16(offWts + 10 * 16384 * 2);
    size_t offOffs   = al16(offCounts + (size_t)N * 4);
    size_t offCursor = al16(offOffs + (size_t)(N + 1) * 4);
    size_t offPerm   = al16(offCursor + (size_t)N * 4);
    size_t offPmeta  = al16(offPerm + (size_t)E * 4);
    size_t offBsum   = al16(offPmeta + (size_t)E * 8);
    size_t need      = offBsum + SCAN_NB * 4;
    if (ws_size < need) return;

    unsigned short* h    = (unsigned short*)(ws + offH);
    unsigned short* a0   = (unsigned short*)(ws + offA0);
    unsigned short* emsg = (unsigned short*)(ws + offEm);
    float* u28    = (float*)(ws + offA0);
    float* stats  = (float*)(ws + offStats);
    short* wts    = (short*)(ws + offWts);
    int*   counts = (int*)(ws + offCounts);
    int*   offs   = (int*)(ws + offOffs);
    int*   cursor = (int*)(ws + offCursor);
    int*   perm   = (int*)(ws + offPerm);
    int2*  pmeta  = (int2*)(ws + offPmeta);
    int*   bsum   = (int*)(ws + offBsum);
    const float4* ea4 = (const float4*)ea;

    hipMemsetAsync(stats, 0, 4 * 256 * sizeof(float), stream);
    hipMemsetAsync(counts, 0, (size_t)N * sizeof(int), stream);
    hipMemsetAsync(d_out, 0, (size_t)S * 128 * sizeof(float), stream);

    k_prep<<<40, 256, 0, stream>>>(m1W2, beW2, mW1, mW2, wts);

    // ---- CSR (dst-sorted edges), 3-phase parallel scan ----
    const int seg = (N + SCAN_NB - 1) / SCAN_NB;
    k_count<<<1024, 256, 0, stream>>>(ei, counts, E);
    k_scanA<<<SCAN_NB, 256, 0, stream>>>(counts, bsum, N, seg);
    k_scanB<<<1, 256, 0, stream>>>(bsum, SCAN_NB, offs, N, E);
    k_scanC<<<SCAN_NB, 256, 0, stream>>>(counts, bsum, offs, cursor, N, seg);
    k_scatter<<<1024, 256, 0, stream>>>(ei, ew, cursor, perm, pmeta, E);

    const short* wt_m1W2 = wts;
    auto wt_be = [&](int l) { return wts + (size_t)(1 + 3 * l + 0) * 16384; };
    auto wt_m1 = [&](int l) { return wts + (size_t)(1 + 3 * l + 1) * 16384; };
    auto wt_m2 = [&](int l) { return wts + (size_t)(1 + 3 * l + 2) * 16384; };

    int gatherBlocks = (N + 7) / 8;

    // ---- layer 1 (28 -> 128) ----
    k_emsg28<<<2048, 256, 0, stream>>>(perm, ea4, be1W1, be1b1, be1W2, be1b2, emsg, E);
    k_gather28<<<gatherBlocks, 256, 0, stream>>>(x, offs, pmeta, emsg, eps1, u28, N);
    k_lin_s<<<1024, 256, 0, stream>>>(u28, m1W1, m1b1, h, N);
    k_mm<<<1024, 256, 0, stream>>>(h, wt_m1W2, m1b2, nullptr, a0, stats, N);
    k_bn<<<2048, 256, 0, stream>>>(a0, stats, bn1g, bn1b, h, a0, epsL, 0,
                                   nullptr, nullptr, nullptr, N, 0, invN);

    // ---- layers 2..4 ----
    for (int l = 0; l < 3; ++l) {
        for (int c = 0; c < 2; ++c) {
            int e0 = c * EC, e1 = min(e0 + EC, E);
            k_emsg<<<2048, 256, 0, stream>>>(perm, ea4,
                beW1 + (size_t)l * 512, beb1 + (size_t)l * 128,
                wt_be(l), beb2 + (size_t)l * 128, emsg, e0, e1);
            k_gather<<<gatherBlocks, 256, 0, stream>>>(h, offs, pmeta, emsg, a0, e0, e1, N);
        }
        k_mm<<<1024, 256, 0, stream>>>(a0, wt_m1(l), mb1 + (size_t)l * 128,
                                       a0, nullptr, nullptr, N);
        k_mm<<<1024, 256, 0, stream>>>(a0, wt_m2(l), mb2 + (size_t)l * 128,
                                       nullptr, a0, stats + 256 * (l + 1), N);
        if (l < 2) {
            k_bn<<<2048, 256, 0, stream>>>(a0, stats + 256 * (l + 1),
                bng + (size_t)l * 128, bnb + (size_t)l * 128,
                h, a0, epsL, l + 1, nullptr, nullptr, nullptr, N, 1, invN);
        } else {
            k_bn<<<2048, 256, 0, stream>>>(a0, stats + 256 * (l + 1),
                bng + (size_t)l * 128, bnb + (size_t)l * 128,
                h, nullptr, epsL, 0, mask, s2n, (float*)d_out, N, 1, invN);
        }
    }
}